// Round 2
// baseline (343.374 us; speedup 1.0000x reference)
//
#include <hip/hip_runtime.h>

namespace {
constexpr int KN = 256;     // K
constexpr int DN = 512;     // D
constexpr int DT = 32;      // d-tile staged in LDS
constexpr int NTILE = DN / DT;
constexpr int NIT = 200;    // FISTA iters
constexpr int PIT = 20;     // power iters
constexpr float FEPS = 1e-8f;

__device__ __forceinline__ float waveSum(float v) {
#pragma unroll
  for (int m = 32; m >= 1; m >>= 1) v += __shfl_xor(v, m, 64);
  return v;
}

// Distributed matvec: out(row k=tid, for tid<K) = sum_j G[k][j] * vbuf[j].
// g: per-thread tile, rows 8*rg..8*rg+7, cols 16*cg..16*cg+15.
__device__ __forceinline__ float matvec(const float (&g)[8][16],
                                        const float* __restrict__ vbuf,
                                        float* __restrict__ red,
                                        int tid, int cg, int wv,
                                        int abase, int skq) {
  float part[8];
#pragma unroll
  for (int i = 0; i < 8; ++i) part[i] = 0.f;
#pragma unroll
  for (int mb = 0; mb < 4; ++mb) {
    const float4 Y = *reinterpret_cast<const float4*>(vbuf + 16 * cg + 4 * mb);
    const float ys[4] = {Y.x, Y.y, Y.z, Y.w};
#pragma unroll
    for (int j = 0; j < 4; ++j)
#pragma unroll
      for (int i = 0; i < 8; ++i)
        part[i] = fmaf(g[i][4 * mb + j], ys[j], part[i]);
  }
  // sum the two half-wave col-groups (cg pairs 2w / 2w+1)
#pragma unroll
  for (int i = 0; i < 8; ++i) part[i] += __shfl_xor(part[i], 32, 64);
  if ((tid & 32) == 0) {
    float4 w0 = make_float4(part[0], part[1], part[2], part[3]);
    float4 w1 = make_float4(part[4], part[5], part[6], part[7]);
    *reinterpret_cast<float4*>(red + wv * KN + abase) = w0;        // swz(8rg+0..3)
    *reinterpret_cast<float4*>(red + wv * KN + (abase ^ 4)) = w1;  // swz(8rg+4..7)
  }
  __syncthreads();
  float out = 0.f;
  if (tid < KN) {
#pragma unroll
    for (int j = 0; j < 8; ++j) out += red[j * KN + skq];
  }
  return out;
}
}  // namespace

extern "C" __global__ void __launch_bounds__(512, 2)
cone_align_kernel(const float* __restrict__ pred,
                  const float* __restrict__ ctr,
                  float* __restrict__ ws_loss) {
  __shared__ alignas(16) float ctr_s[DT * KN];  // [dd][k], k swizzled
  __shared__ alignas(16) float cpbuf[DN];       // cp = -pred (plain)
  __shared__ alignas(16) float yv[KN];          // v / y vector (plain)
  __shared__ alignas(16) float lamv[KN];        // lambda (plain)
  __shared__ alignas(16) float bvv[KN];         // b = ctr . cp (plain)
  __shared__ alignas(16) float red[8 * KN];     // per-wave matvec partials, k swizzled
  __shared__ alignas(16) float red2[8];
  __shared__ alignas(16) float sc[4];  // 0: ||cp||^2, 1: power scale / step, 2: P2

  const int tid = threadIdx.x;
  const int s = blockIdx.x;
  const int rg = tid & 31;   // row group: rows 8*rg..8*rg+7
  const int cg = tid >> 5;   // col group 0..15: cols 16*cg..16*cg+15
  const int wv = tid >> 6;   // wave 0..7
  // swzk(k) = k ^ (((k>>5)&7)<<2)  (bijective involution on 0..255)
  const int abase = (8 * rg) ^ (((rg >> 2) & 7) << 2);
  const int bbase = (16 * cg) ^ (((cg >> 1) & 7) << 2);
  const int skq = tid ^ (((tid >> 5) & 7) << 2);  // swzk(tid), used when tid<KN

  // ---- cp = -pred, ||cp||^2 ----
  const float cpval = -pred[(size_t)s * DN + tid];
  cpbuf[tid] = cpval;
  {
    const float v = waveSum(cpval * cpval);
    if ((tid & 63) == 0) red2[wv] = v;
  }
  __syncthreads();
  if (tid == 0) {
    float t = 0.f;
#pragma unroll
    for (int j = 0; j < 8; ++j) t += red2[j];
    sc[0] = t;
  }

  // ---- Gram phase: G distributed in registers, b accumulated during staging ----
  float g[8][16];
#pragma unroll
  for (int i = 0; i < 8; ++i)
#pragma unroll
    for (int m = 0; m < 16; ++m) g[i][m] = 0.f;

  const int kst = tid >> 1;  // staging row (2 threads per row)
  const int hst = tid & 1;
  const int skw = kst ^ (((kst >> 5) & 7) << 2);
  const float* ctrS = ctr + (size_t)s * KN * DN;
  float bacc = 0.f;

  for (int ti = 0; ti < NTILE; ++ti) {
    const int d0 = ti * DT;
    __syncthreads();  // previous tile fully consumed
#pragma unroll
    for (int c = 0; c < 4; ++c) {
      const int f = hst + 2 * c;  // float4 index 0..7 within tile row
      const float4 v = *reinterpret_cast<const float4*>(
          ctrS + (size_t)kst * DN + d0 + 4 * f);
      ctr_s[(4 * f + 0) * KN + skw] = v.x;
      ctr_s[(4 * f + 1) * KN + skw] = v.y;
      ctr_s[(4 * f + 2) * KN + skw] = v.z;
      ctr_s[(4 * f + 3) * KN + skw] = v.w;
      bacc = fmaf(v.x, cpbuf[d0 + 4 * f + 0], bacc);
      bacc = fmaf(v.y, cpbuf[d0 + 4 * f + 1], bacc);
      bacc = fmaf(v.z, cpbuf[d0 + 4 * f + 2], bacc);
      bacc = fmaf(v.w, cpbuf[d0 + 4 * f + 3], bacc);
    }
    __syncthreads();
#pragma unroll 2
    for (int dd = 0; dd < DT; ++dd) {
      const float* row = ctr_s + dd * KN;
      const float4 A0 = *reinterpret_cast<const float4*>(row + abase);
      const float4 A1 = *reinterpret_cast<const float4*>(row + (abase ^ 4));
      const float4 B0 = *reinterpret_cast<const float4*>(row + bbase);
      const float4 B1 = *reinterpret_cast<const float4*>(row + (bbase ^ 4));
      const float4 B2 = *reinterpret_cast<const float4*>(row + (bbase ^ 8));
      const float4 B3 = *reinterpret_cast<const float4*>(row + (bbase ^ 12));
      const float av[8] = {A0.x, A0.y, A0.z, A0.w, A1.x, A1.y, A1.z, A1.w};
      const float bv[16] = {B0.x, B0.y, B0.z, B0.w, B1.x, B1.y, B1.z, B1.w,
                            B2.x, B2.y, B2.z, B2.w, B3.x, B3.y, B3.z, B3.w};
#pragma unroll
      for (int i = 0; i < 8; ++i)
#pragma unroll
        for (int m = 0; m < 16; ++m) g[i][m] = fmaf(av[i], bv[m], g[i][m]);
    }
  }
  // combine the two per-row b partials (pair tid, tid^1)
  {
    const float bo = __shfl_xor(bacc, 1, 64);
    if (hst == 0) bvv[kst] = bacc + bo;
  }
  if (tid < KN) yv[tid] = 1.0f;  // power iteration v0 = ones
  __syncthreads();

  // ---- power iteration (20 normalized steps + 1 for L) ----
  for (int it = 0; it <= PIT; ++it) {
    const float wk = matvec(g, yv, red, tid, cg, wv, abase, skq);
    const float n2 = waveSum(tid < KN ? wk * wk : 0.f);
    if ((tid & 63) == 0) red2[wv] = n2;
    __syncthreads();
    if (tid == 0) {
      float t = 0.f;
#pragma unroll
      for (int j = 0; j < 8; ++j) t += red2[j];
      const float n = sqrtf(t);
      sc[1] = (it < PIT) ? 1.0f / (n + FEPS)           // v normalize scale
                         : 1.0f / (n * 1.01f + FEPS);  // final: step = 1/L
    }
    __syncthreads();
    if (it < PIT && tid < KN) yv[tid] = wk * sc[1];
    __syncthreads();
  }

  // ---- FISTA ----
  if (tid < KN) {
    yv[tid] = 0.f;
    lamv[tid] = 0.f;
  }
  __syncthreads();
  const float step = sc[1];
  float t = 1.0f;
  for (int it = 0; it < NIT; ++it) {
    const float s1 = matvec(g, yv, red, tid, cg, wv, abase, skq);
    if (tid < KN) {
      const float grad = s1 - bvv[tid];
      const float yk = yv[tid];
      const float lo = lamv[tid];
      const float ln = fmaxf(yk - step * grad, 0.f);
      const float tn = 0.5f * (1.0f + sqrtf(1.0f + 4.0f * t * t));
      const float yn = ln + ((t - 1.0f) / tn) * (ln - lo);
      lamv[tid] = ln;
      yv[tid] = yn;
      t = tn;
    }
    __syncthreads();
  }

  // ---- epilogue: P2 = lam^T G lam, S = lam.b, loss from scalars ----
  float acc = 0.f;
  {
    const float4 L0 = *reinterpret_cast<const float4*>(lamv + 8 * rg);
    const float4 L1 = *reinterpret_cast<const float4*>(lamv + 8 * rg + 4);
    const float4 C0 = *reinterpret_cast<const float4*>(lamv + 16 * cg);
    const float4 C1 = *reinterpret_cast<const float4*>(lamv + 16 * cg + 4);
    const float4 C2 = *reinterpret_cast<const float4*>(lamv + 16 * cg + 8);
    const float4 C3 = *reinterpret_cast<const float4*>(lamv + 16 * cg + 12);
    const float lr[8] = {L0.x, L0.y, L0.z, L0.w, L1.x, L1.y, L1.z, L1.w};
    const float lc[16] = {C0.x, C0.y, C0.z, C0.w, C1.x, C1.y, C1.z, C1.w,
                          C2.x, C2.y, C2.z, C2.w, C3.x, C3.y, C3.z, C3.w};
#pragma unroll
    for (int i = 0; i < 8; ++i) {
      float ri = 0.f;
#pragma unroll
      for (int m = 0; m < 16; ++m) ri = fmaf(g[i][m], lc[m], ri);
      acc = fmaf(lr[i], ri, acc);
    }
  }
  {
    const float p2 = waveSum(acc);
    if ((tid & 63) == 0) red2[wv] = p2;
  }
  __syncthreads();
  if (tid == 0) {
    float t2 = 0.f;
#pragma unroll
    for (int j = 0; j < 8; ++j) t2 += red2[j];
    sc[2] = t2;
  }
  __syncthreads();
  {
    const float sv = waveSum(tid < KN ? lamv[tid] * bvv[tid] : 0.f);
    if ((tid & 63) == 0) red2[wv] = sv;
  }
  __syncthreads();
  if (tid == 0) {
    float S = 0.f;
#pragma unroll
    for (int j = 0; j < 8; ++j) S += red2[j];
    const float P = sqrtf(fmaxf(sc[2], 0.f));
    const float C = sqrtf(sc[0]);
    const float num = S / (P + FEPS);
    const float den = fmaxf(C, FEPS) * fmaxf(P / (P + FEPS), FEPS);
    ws_loss[s] = -(num / den);
  }
}

extern "C" __global__ void reduce_loss_kernel(const float* __restrict__ ws,
                                              float* __restrict__ out) {
  const int tid = threadIdx.x;  // 256 threads
  float v = ws[tid];
  v = waveSum(v);
  __shared__ float r[4];
  if ((tid & 63) == 0) r[tid >> 6] = v;
  __syncthreads();
  if (tid == 0) out[0] = (r[0] + r[1] + r[2] + r[3]) * (1.0f / 256.0f);
}

extern "C" void kernel_launch(void* const* d_in, const int* in_sizes, int n_in,
                              void* d_out, int out_size, void* d_ws, size_t ws_size,
                              hipStream_t stream) {
  (void)in_sizes; (void)n_in; (void)out_size; (void)ws_size;
  const float* pred = (const float*)d_in[0];
  const float* ctr = (const float*)d_in[1];
  float* out = (float*)d_out;
  float* ws = (float*)d_ws;
  hipLaunchKernelGGL(cone_align_kernel, dim3(256), dim3(512), 0, stream,
                     pred, ctr, ws);
  hipLaunchKernelGGL(reduce_loss_kernel, dim3(1), dim3(256), 0, stream, ws, out);
}

// Round 3
// 328.535 us; speedup vs baseline: 1.0452x; 1.0452x over previous
//
#include <hip/hip_runtime.h>

namespace {
constexpr int KN = 256;
constexpr int DN = 512;
constexpr int NIT = 200;
constexpr int PIT = 20;
constexpr float FEPS = 1e-8f;
constexpr int YSTR = 20;  // padded stride for transposed y vector (16 + 4 pad)

typedef __attribute__((ext_vector_type(8))) short short8v;
typedef __attribute__((ext_vector_type(4))) float f32x4;

__device__ __forceinline__ float waveSum(float v) {
#pragma unroll
  for (int m = 32; m >= 1; m >>= 1) v += __shfl_xor(v, m, 64);
  return v;
}
__device__ __forceinline__ unsigned short f2bf(float x) {  // RNE, no NaN inputs
  unsigned u = __float_as_uint(x);
  u += 0x7FFFu + ((u >> 16) & 1u);
  return (unsigned short)(u >> 16);
}
__device__ __forceinline__ float bf2f(unsigned short h) {
  return __uint_as_float(((unsigned)h) << 16);
}

// dot[i] = row-dot of G row (32w+16ti+4qg+r) with y, using MFMA C-layout regs.
// After 4 shfl_xor rounds all 16 lanes of a qg-group hold the full row dots.
__device__ __forceinline__ void matvec8(const f32x4 (&acc)[2][16],
                                        const float* __restrict__ ybuf,
                                        int cq, float (&dot)[8]) {
  float yc[16];
#pragma unroll
  for (int m = 0; m < 4; ++m) {
    const f32x4 Y = *reinterpret_cast<const f32x4*>(ybuf + YSTR * cq + 4 * m);
#pragma unroll
    for (int j = 0; j < 4; ++j) yc[4 * m + j] = Y[j];
  }
#pragma unroll
  for (int i = 0; i < 8; ++i) dot[i] = 0.f;
#pragma unroll
  for (int tj = 0; tj < 16; ++tj)
#pragma unroll
    for (int ti = 0; ti < 2; ++ti)
#pragma unroll
      for (int r2 = 0; r2 < 4; ++r2)
        dot[ti * 4 + r2] = fmaf(acc[ti][tj][r2], yc[tj], dot[ti * 4 + r2]);
#pragma unroll
  for (int m = 1; m <= 8; m <<= 1)
#pragma unroll
    for (int i = 0; i < 8; ++i) dot[i] += __shfl_xor(dot[i], m, 64);
}
}  // namespace

extern "C" __global__ void __launch_bounds__(512, 2)
cone_align_kernel(const float* __restrict__ pred,
                  const float* __restrict__ ctr,
                  float* __restrict__ ws_loss) {
  __shared__ alignas(16) short Ah[KN * 32];   // bf16 hi plane, [row][32 k]
  __shared__ alignas(16) short Al[KN * 32];   // bf16 lo plane
  __shared__ alignas(16) float cpbuf[DN];
  __shared__ alignas(16) float vy[2][16 * YSTR];  // transposed y, double-buffered
  __shared__ alignas(16) float bvv[KN];
  __shared__ float redA[8], redB[8], sc[2];

  const int tid = threadIdx.x;
  const int s = blockIdx.x;
  const int l = tid & 63;
  const int w = tid >> 6;
  const int cq = l & 15;  // col class (MFMA C-layout: col = 16*tj + cq)
  const int qg = l >> 4;  // row quarter (rows 32w+16ti+4qg+r)

  // ---- cp = -pred, ||cp||^2 ----
  const float cpval = -pred[(size_t)s * DN + tid];
  cpbuf[tid] = cpval;
  {
    const float v = waveSum(cpval * cpval);
    if (l == 0) redA[w] = v;
  }
  __syncthreads();
  float cp2 = 0.f;
  if (tid == 0) {
#pragma unroll
    for (int j = 0; j < 8; ++j) cp2 += redA[j];
  }

  // ---- Gram via MFMA (hi/lo bf16 split, 3 terms) ----
  f32x4 acc[2][16];
#pragma unroll
  for (int ti = 0; ti < 2; ++ti)
#pragma unroll
    for (int tj = 0; tj < 16; ++tj) acc[ti][tj] = (f32x4){0.f, 0.f, 0.f, 0.f};

  const float* ctrS = ctr + (size_t)s * KN * DN;
  const int rS = tid >> 1, hS = tid & 1;  // staging: row, 16-col half
  float bacc = 0.f;

  for (int ks = 0; ks < 16; ++ks) {
    const int k0 = 32 * ks;
    __syncthreads();  // previous tile fully consumed
    {
      const float4* gp = reinterpret_cast<const float4*>(
          ctrS + (size_t)rS * DN + k0 + 16 * hS);
      float va[16];
#pragma unroll
      for (int m = 0; m < 4; ++m) {
        const float4 v = gp[m];
        va[4 * m + 0] = v.x; va[4 * m + 1] = v.y;
        va[4 * m + 2] = v.z; va[4 * m + 3] = v.w;
      }
      unsigned short hi[16], lo[16];
#pragma unroll
      for (int j = 0; j < 16; ++j) {
        bacc = fmaf(va[j], cpbuf[k0 + 16 * hS + j], bacc);
        const unsigned short hv = f2bf(va[j]);
        hi[j] = hv;
        lo[j] = f2bf(va[j] - bf2f(hv));
      }
      short8v ph0, ph1, pl0, pl1;
#pragma unroll
      for (int j = 0; j < 8; ++j) {
        ph0[j] = (short)hi[j]; ph1[j] = (short)hi[8 + j];
        pl0[j] = (short)lo[j]; pl1[j] = (short)lo[8 + j];
      }
      *reinterpret_cast<short8v*>(&Ah[rS * 32 + 16 * hS]) = ph0;
      *reinterpret_cast<short8v*>(&Ah[rS * 32 + 16 * hS + 8]) = ph1;
      *reinterpret_cast<short8v*>(&Al[rS * 32 + 16 * hS]) = pl0;
      *reinterpret_cast<short8v*>(&Al[rS * 32 + 16 * hS + 8]) = pl1;
    }
    __syncthreads();
    short8v aH[2], aL[2];
#pragma unroll
    for (int ti = 0; ti < 2; ++ti) {
      const int rr = 32 * w + 16 * ti + cq;
      aH[ti] = *reinterpret_cast<const short8v*>(&Ah[rr * 32 + 8 * qg]);
      aL[ti] = *reinterpret_cast<const short8v*>(&Al[rr * 32 + 8 * qg]);
    }
#pragma unroll
    for (int tj = 0; tj < 16; ++tj) {
      const int rc = 16 * tj + cq;
      const short8v bH = *reinterpret_cast<const short8v*>(&Ah[rc * 32 + 8 * qg]);
      const short8v bL = *reinterpret_cast<const short8v*>(&Al[rc * 32 + 8 * qg]);
#pragma unroll
      for (int ti = 0; ti < 2; ++ti) {
        acc[ti][tj] = __builtin_amdgcn_mfma_f32_16x16x32_bf16(aH[ti], bH, acc[ti][tj], 0, 0, 0);
        acc[ti][tj] = __builtin_amdgcn_mfma_f32_16x16x32_bf16(aH[ti], bL, acc[ti][tj], 0, 0, 0);
        acc[ti][tj] = __builtin_amdgcn_mfma_f32_16x16x32_bf16(aL[ti], bH, acc[ti][tj], 0, 0, 0);
      }
    }
  }

  // ---- b finalize (pair-sum), power-iter v0 = ones ----
  {
    const float bo = __shfl_xor(bacc, 1, 64);
    if (hS == 0) bvv[rS] = bacc + bo;
  }
  if (tid < 16 * YSTR) vy[0][tid] = 1.0f;
  __syncthreads();

  float breg[8];
#pragma unroll
  for (int ti = 0; ti < 2; ++ti)
#pragma unroll
    for (int r2 = 0; r2 < 4; ++r2)
      breg[ti * 4 + r2] = bvv[32 * w + 16 * ti + 4 * qg + r2];

  // ---- power iteration, fixed 1/1024 scaling (direction identical to ref) ----
  float wrow[8];
#pragma unroll
  for (int i = 0; i < 8; ++i) wrow[i] = 1.0f;
  int pb = 0;
  for (int it = 0; it < PIT; ++it) {
    float dot[8];
    matvec8(acc, vy[pb], cq, dot);
#pragma unroll
    for (int i = 0; i < 8; ++i) wrow[i] = dot[i] * (1.0f / 1024.0f);
    if (cq == 0) {
#pragma unroll
      for (int ti = 0; ti < 2; ++ti)
#pragma unroll
        for (int r2 = 0; r2 < 4; ++r2)
          vy[pb ^ 1][YSTR * (4 * qg + r2) + 2 * w + ti] = wrow[ti * 4 + r2];
    }
    __syncthreads();
    pb ^= 1;
  }
  {  // L = ||G w|| / ||w|| * 1.01 + eps
    float dot[8];
    matvec8(acc, vy[pb], cq, dot);
    float u2 = 0.f, w2 = 0.f;
    if (cq == 0) {
#pragma unroll
      for (int i = 0; i < 8; ++i) {
        u2 = fmaf(dot[i], dot[i], u2);
        w2 = fmaf(wrow[i], wrow[i], w2);
      }
    }
    u2 = waveSum(u2);
    w2 = waveSum(w2);
    if (l == 0) { redA[w] = u2; redB[w] = w2; }
  }
  __syncthreads();  // all matvec reads of vy[0] done; redA/redB published
  if (tid == 0) {
    float U2 = 0.f, W2 = 0.f;
#pragma unroll
    for (int j = 0; j < 8; ++j) { U2 += redA[j]; W2 += redB[j]; }
    const float L = sqrtf(U2) / (sqrtf(W2) + FEPS) * 1.01f + FEPS;
    sc[1] = 1.0f / L;
  }
  if (tid < 16 * YSTR) vy[0][tid] = 0.0f;  // FISTA y0 = 0 (safe: reads drained)
  __syncthreads();

  // ---- FISTA ----
  const float stepv = sc[1];
  float lamrow[8], yrow[8];
#pragma unroll
  for (int i = 0; i < 8; ++i) { lamrow[i] = 0.f; yrow[i] = 0.f; }
  float tF = 1.0f;
  pb = 0;
  for (int it = 0; it < NIT; ++it) {
    float dot[8];
    matvec8(acc, vy[pb], cq, dot);
    const float tn = 0.5f * (1.0f + sqrtf(1.0f + 4.0f * tF * tF));
    const float cf = (tF - 1.0f) / tn;
#pragma unroll
    for (int i = 0; i < 8; ++i) {
      const float grad = dot[i] - breg[i];
      const float ln = fmaxf(yrow[i] - stepv * grad, 0.f);
      const float yn = ln + cf * (ln - lamrow[i]);
      lamrow[i] = ln;
      yrow[i] = yn;
    }
    if (cq == 0) {
#pragma unroll
      for (int ti = 0; ti < 2; ++ti)
#pragma unroll
        for (int r2 = 0; r2 < 4; ++r2)
          vy[pb ^ 1][YSTR * (4 * qg + r2) + 2 * w + ti] = yrow[ti * 4 + r2];
    }
    __syncthreads();
    pb ^= 1;
    tF = tn;
  }

  // ---- epilogue: S = lam.b, P2 = lam^T G lam ----
  if (cq == 0) {  // publish lambda transposed (overwrite vy[0]; all reads drained)
#pragma unroll
    for (int ti = 0; ti < 2; ++ti)
#pragma unroll
      for (int r2 = 0; r2 < 4; ++r2)
        vy[0][YSTR * (4 * qg + r2) + 2 * w + ti] = lamrow[ti * 4 + r2];
  }
  __syncthreads();
  float lamcol[16];
#pragma unroll
  for (int m = 0; m < 4; ++m) {
    const f32x4 Y = *reinterpret_cast<const f32x4*>(&vy[0][YSTR * cq + 4 * m]);
#pragma unroll
    for (int j = 0; j < 4; ++j) lamcol[4 * m + j] = Y[j];
  }
  float p2 = 0.f;
#pragma unroll
  for (int ti = 0; ti < 2; ++ti)
#pragma unroll
    for (int r2 = 0; r2 < 4; ++r2) {
      float rowdot = 0.f;
#pragma unroll
      for (int tj = 0; tj < 16; ++tj)
        rowdot = fmaf(acc[ti][tj][r2], lamcol[tj], rowdot);
      p2 = fmaf(lamrow[ti * 4 + r2], rowdot, p2);
    }
  float sp = 0.f;
  if (cq == 0) {
#pragma unroll
    for (int i = 0; i < 8; ++i) sp = fmaf(lamrow[i], breg[i], sp);
  }
  p2 = waveSum(p2);
  sp = waveSum(sp);
  if (l == 0) { redA[w] = p2; redB[w] = sp; }
  __syncthreads();
  if (tid == 0) {
    float P2 = 0.f, S = 0.f;
#pragma unroll
    for (int j = 0; j < 8; ++j) { P2 += redA[j]; S += redB[j]; }
    const float P = sqrtf(fmaxf(P2, 0.f));
    const float C = sqrtf(cp2);
    const float num = S / (P + FEPS);
    const float den = fmaxf(C, FEPS) * fmaxf(P / (P + FEPS), FEPS);
    ws_loss[s] = -(num / den);
  }
}

extern "C" __global__ void reduce_loss_kernel(const float* __restrict__ ws,
                                              float* __restrict__ out) {
  const int tid = threadIdx.x;  // 256 threads
  float v = ws[tid];
  v = waveSum(v);
  __shared__ float r[4];
  if ((tid & 63) == 0) r[tid >> 6] = v;
  __syncthreads();
  if (tid == 0) out[0] = (r[0] + r[1] + r[2] + r[3]) * (1.0f / 256.0f);
}

extern "C" void kernel_launch(void* const* d_in, const int* in_sizes, int n_in,
                              void* d_out, int out_size, void* d_ws, size_t ws_size,
                              hipStream_t stream) {
  (void)in_sizes; (void)n_in; (void)out_size; (void)ws_size;
  const float* pred = (const float*)d_in[0];
  const float* ctr = (const float*)d_in[1];
  float* out = (float*)d_out;
  float* ws = (float*)d_ws;
  hipLaunchKernelGGL(cone_align_kernel, dim3(256), dim3(512), 0, stream,
                     pred, ctr, ws);
  hipLaunchKernelGGL(reduce_loss_kernel, dim3(1), dim3(256), 0, stream, ws, out);
}